// Round 8
// baseline (180.695 us; speedup 1.0000x reference)
//
#include <hip/hip_runtime.h>

// Problem constants (match reference setup_inputs)
#define BB 16
#define SS 2048
#define DD 768
#define D4 (DD / 4)        // 192 float4 per row
#define RB 16              // rows per block (16 x 3072B = 48KB LDS tile)
#define RW 4               // rows per wave (RB / 4 waves)
#define OUT_F4 (BB * SS * DD / 4)   // 6291456 float4 in out

#define ADD4(A, R) { A.x += R.x; A.y += R.y; A.z += R.z; A.w += R.w; }

// Async global->LDS, 16B per lane, wave-uniform LDS base + lane*16.
#define GLOAD_LDS16(gaddr, laddr)                                              \
    __builtin_amdgcn_global_load_lds(                                          \
        (const __attribute__((address_space(1))) void*)(gaddr),                \
        (__attribute__((address_space(3))) void*)(laddr), 16, 0, 0)

// ---------------------------------------------------------------------------
// Pass 1: dense zero-fill of out. Mimics the vendor fillBufferAligned pattern
// (grid-stride dwordx4 stores), which measures 6.7 TB/s in this harness.
// Covers every empty slot and every gap — pass 2 then only writes mean rows.
// ---------------------------------------------------------------------------
__global__ __launch_bounds__(256) void zero_out(float4* __restrict__ out) {
    int idx    = blockIdx.x * 256 + threadIdx.x;
    int stride = gridDim.x * 256;
    const float4 zz = make_float4(0.f, 0.f, 0.f, 0.f);
    for (int i = idx; i < OUT_F4; i += stride)
        out[i] = zz;
}

// ---------------------------------------------------------------------------
// Pass 2: v6's LDS-staged run-sum structure, zero-fill logic deleted.
// Writes ONLY the mean rows (~63% of slots): WRITE drops 98 -> ~62 MB and the
// store stream has no data-dependent gap bursts.
// ---------------------------------------------------------------------------
__device__ __forceinline__ void emit_mean(float* __restrict__ ob, int v, int c,
                                          float4 a0, float4 a1, float4 a2,
                                          int lane) {
    float inv = 1.0f / (float)c;
    a0.x *= inv; a0.y *= inv; a0.z *= inv; a0.w *= inv;
    a1.x *= inv; a1.y *= inv; a1.z *= inv; a1.w *= inv;
    a2.x *= inv; a2.y *= inv; a2.z *= inv; a2.w *= inv;
    float4* op = (float4*)(ob + (size_t)v * DD);
    op[lane]       = a0;
    op[lane + 64]  = a1;
    op[lane + 128] = a2;
}

__global__ __launch_bounds__(256) void seg_mean_v7(
    const float* __restrict__ x,
    const int*   __restrict__ seg,
    float*       __restrict__ out) {
    __shared__ float lds[RB * DD];             // 49152 B
    int lane = threadIdx.x & 63;
    int wv   = threadIdx.x >> 6;
    int p0   = blockIdx.x * RB;                // global first position
    int b    = p0 >> 11;                       // / SS  (blocks never cross rows)
    int q0   = p0 & (SS - 1);                  // position within batch row
    const int*   srow = seg + (b << 11);
    const float* xb   = x   + (size_t)(b << 11) * DD;
    float*       ob   = out + (size_t)(b << 11) * DD;

    // ---- LOAD PHASE: wave wv stages rows [wv*RW, wv*RW+RW) into LDS ----
    {
        const float* gsrc = xb + (size_t)(q0 + wv * RW) * DD + lane * 4;
        float*       ldst = lds + (wv * RW) * DD;
        #pragma unroll
        for (int k = 0; k < RW * 3; ++k) {     // 12 x 1024B per wave
            GLOAD_LDS16(gsrc + k * 256, ldst + k * 256);
        }
    }

    // ---- Run-start detection over the block's RB positions (overlaps loads)
    int  myv = 0;
    bool startl = false;
    if (lane < RB) {
        int p = q0 + lane;
        myv = srow[p];
        int pv = (p == 0) ? (myv ^ 1) : srow[p - 1];  // force start at p==0
        startl = (myv != pv);
    }
    unsigned long long smask = __ballot(startl);      // bits 0..RB-1

    __syncthreads();                           // vmcnt(0): LDS tile ready

    // ---- COMPUTE PHASE: wave wv owns runs starting in [wv*RW, wv*RW+RW) ----
    unsigned wmask = (unsigned)(smask >> (wv * RW)) & ((1u << RW) - 1);
    while (wmask) {
        int jrel = __builtin_ctz(wmask); wmask &= wmask - 1;
        int j    = wv * RW + jrel;             // block-local run start
        int vcur = __shfl(myv, j);

        unsigned long long above = smask >> (j + 1);
        int  e_loc;
        bool tail;
        if (above) { e_loc = j + 1 + (int)__builtin_ctzll(above); tail = false; }
        else       { e_loc = RB;                                  tail = true;  }

        // Sum rows [j, e_loc) from LDS
        const float4* lp = (const float4*)(lds + (size_t)j * DD);
        float4 a0 = lp[lane], a1 = lp[lane + 64], a2 = lp[lane + 128];
        for (int t = j + 1; t < e_loc; ++t) {
            const float4* q = (const float4*)(lds + (size_t)t * DD);
            float4 r0 = q[lane], r1 = q[lane + 64], r2 = q[lane + 128];
            ADD4(a0, r0); ADD4(a1, r1); ADD4(a2, r2);
        }

        int c;
        if (!tail) {
            c = e_loc - j;
        } else {
            // Run may extend past the tile: scan seg, sum extra rows from global
            int e = q0 + RB;
            if (e < SS) {
                for (;;) {
                    int idx = e + lane;
                    int vv  = (idx < SS) ? srow[idx] : (vcur ^ 1);  // OOB != vcur
                    unsigned long long m  = __ballot(vv == vcur);
                    unsigned long long nm = ~m;
                    if (nm) { e += (int)__builtin_ctzll(nm); break; }
                    e += 64;
                }
            }
            for (int t = q0 + RB; t < e; ++t) {
                const float4* xn = (const float4*)(xb + (size_t)t * DD);
                float4 r0 = xn[lane], r1 = xn[lane + 64], r2 = xn[lane + 128];
                ADD4(a0, r0); ADD4(a1, r1); ADD4(a2, r2);
            }
            c = e - (q0 + j);
        }
        emit_mean(ob, vcur, c, a0, a1, a2, lane);
    }
}

extern "C" void kernel_launch(void* const* d_in, const int* in_sizes, int n_in,
                              void* d_out, int out_size, void* d_ws, size_t ws_size,
                              hipStream_t stream) {
    const float* x   = (const float*)d_in[0];   // [B,S,D] fp32
    const int*   seg = (const int*)d_in[1];     // [B,S] int32
    float* out = (float*)d_out;                 // [B,S,D] fp32

    // Pass 1: zero everything (dense pure-write burst, vendor-fill pattern).
    zero_out<<<2048, 256, 0, stream>>>((float4*)out);
    // Pass 2: compute + write only the mean rows (stream-ordered after pass 1).
    int nBlocks = (BB * SS) / RB;               // 2048
    seg_mean_v7<<<nBlocks, 256, 0, stream>>>(x, seg, out);
}